// Round 3
// baseline (1324.824 us; speedup 1.0000x reference)
//
#include <hip/hip_runtime.h>

#define N_NODESC 100000
#define N_EDGESC 1600000
#define N_GRAPHSC 64
#define HIDC 128
#define NCLSC 696

typedef __attribute__((ext_vector_type(8))) short short8;
typedef __attribute__((ext_vector_type(4))) float f32x4;

__device__ __forceinline__ ushort f2b(float x) {
  union { float f; unsigned u; } a; a.f = x;
  unsigned r = a.u + 0x7FFFu + ((a.u >> 16) & 1u);
  return (ushort)(r >> 16);
}
__device__ __forceinline__ float b2f(ushort b) {
  union { float f; unsigned u; } a; a.u = ((unsigned)b) << 16;
  return a.f;
}

// ---------------- CSR build ----------------
__global__ void k_hist(const int* __restrict__ ei, int* __restrict__ cnt, int E) {
  int e = blockIdx.x * 256 + threadIdx.x;
  if (e < E) atomicAdd(&cnt[ei[E + e] + 1], 1);
}

__global__ __launch_bounds__(1024) void k_scan1(const int* __restrict__ cnt,
                                                int* __restrict__ rowptr,
                                                int* __restrict__ bsums, int n) {
  __shared__ int wsum[16];
  int t = threadIdx.x, b = blockIdx.x;
  int i = b * 1024 + t;
  int v = (i < n) ? cnt[i] : 0;
  int lane = t & 63, w = t >> 6;
  for (int d = 1; d < 64; d <<= 1) {
    int u = __shfl_up(v, (unsigned)d, 64);
    if (lane >= d) v += u;
  }
  if (lane == 63) wsum[w] = v;
  __syncthreads();
  if (w == 0) {
    int s = (lane < 16) ? wsum[lane] : 0;
    for (int d = 1; d < 16; d <<= 1) {
      int u = __shfl_up(s, (unsigned)d, 64);
      if (lane >= d) s += u;
    }
    if (lane < 16) wsum[lane] = s;
  }
  __syncthreads();
  int add = (w > 0) ? wsum[w - 1] : 0;
  v += add;
  if (i < n) rowptr[i] = v;
  if (t == 1023) bsums[b] = v;
}

__global__ void k_scan2(int* bsums, int nb) {
  if (threadIdx.x == 0) {
    int s = 0;
    for (int i = 0; i < nb; ++i) { s += bsums[i]; bsums[i] = s; }
  }
}

__global__ __launch_bounds__(1024) void k_scan3(int* __restrict__ rowptr,
                                                const int* __restrict__ bsums,
                                                int* __restrict__ cursor, int n) {
  int b = blockIdx.x;
  int i = b * 1024 + threadIdx.x;
  if (i >= n) return;
  int off = (b > 0) ? bsums[b - 1] : 0;
  int v = rowptr[i] + off;
  rowptr[i] = v;
  cursor[i] = v;
}

__global__ void k_scatter(const int* __restrict__ ei, int* __restrict__ cursor,
                          int* __restrict__ col, int E) {
  int e = blockIdx.x * 256 + threadIdx.x;
  if (e < E) {
    int d = ei[E + e];
    int pos = atomicAdd(&cursor[d], 1);
    col[pos] = ei[e];  // src
  }
}

// ---------------- weight split (transpose + hi/lo bf16) ----------------
__global__ void k_wsplit(const float* __restrict__ W1s, const float* __restrict__ W2s,
                         ushort* __restrict__ hi, ushort* __restrict__ lo) {
  int idx = blockIdx.x * 256 + threadIdx.x;  // 8*16384
  if (idx >= 8 * 16384) return;
  int m = idx >> 14;
  int r = (idx >> 7) & 127;  // n (output col)
  int k = idx & 127;
  const float* W = (m < 4) ? (W1s + (size_t)m * 16384) : (W2s + (size_t)(m - 4) * 16384);
  float v = W[k * 128 + r];
  ushort vh = f2b(v);
  float res = v - b2f(vh);
  hi[idx] = vh;
  lo[idx] = f2b(res);
}

// ---------------- fused GIN layer: aggregate + MLP(2x GEMM, relu) ----------------
// hout[node] = relu( relu( (h[node]+sum_nbr h) @ W1 + b1 ) @ W2 + b2 )
__global__ __launch_bounds__(256) void k_layer(const float* __restrict__ hin,
                                               const int* __restrict__ rowptr,
                                               const int* __restrict__ col,
                                               const ushort* __restrict__ W1hi,
                                               const ushort* __restrict__ W1lo,
                                               const ushort* __restrict__ W2hi,
                                               const ushort* __restrict__ W2lo,
                                               const float* __restrict__ bias1,
                                               const float* __restrict__ bias2,
                                               float* __restrict__ hout, int M) {
  __shared__ __align__(16) char smem[34816];
  ushort* ahi = (ushort*)smem;            // [64][136]
  ushort* alo = ahi + 64 * 136;           // [64][136]
  float* ldsC = (float*)smem;             // [64][132] (reused at the end)

  int t = threadIdx.x;
  int lane = t & 63, w = t >> 6;
  int row0 = blockIdx.x * 64;

  // ---- phase 1: aggregation, 16 rows per wave, split to hi/lo bf16 in LDS ----
  {
    const float2* base = (const float2*)hin;
    for (int r = w * 16; r < w * 16 + 16; ++r) {
      int node = row0 + r;
      if (node >= M) node = M - 1;
      float2 self = base[(size_t)node * 64 + lane];
      float accx = self.x, accy = self.y;
      int j = rowptr[node], e = rowptr[node + 1];
      for (; j + 4 <= e; j += 4) {
        int s0 = col[j], s1 = col[j + 1], s2 = col[j + 2], s3 = col[j + 3];
        float2 v0 = base[(size_t)s0 * 64 + lane];
        float2 v1 = base[(size_t)s1 * 64 + lane];
        float2 v2 = base[(size_t)s2 * 64 + lane];
        float2 v3 = base[(size_t)s3 * 64 + lane];
        accx += (v0.x + v1.x) + (v2.x + v3.x);
        accy += (v0.y + v1.y) + (v2.y + v3.y);
      }
      for (; j < e; ++j) {
        float2 v = base[(size_t)col[j] * 64 + lane];
        accx += v.x; accy += v.y;
      }
      // split to hi/lo, write 2 cols (2*lane, 2*lane+1) as one u32 each
      ushort hx = f2b(accx), hy = f2b(accy);
      ushort lx = f2b(accx - b2f(hx)), ly = f2b(accy - b2f(hy));
      ((uint*)&ahi[r * 136 + 2 * lane])[0] = (uint)hx | ((uint)hy << 16);
      ((uint*)&alo[r * 136 + 2 * lane])[0] = (uint)lx | ((uint)ly << 16);
    }
  }
  __syncthreads();

  int lrow = w * 16 + (lane & 15);
  int koff = (lane >> 4) * 8;
  int lbase = lrow * 136;
  int colb = lane & 15;
  int rbase = (lane >> 4) * 4;

  // ---- phase 2: GEMM1 = relu(Z @ W1 + b1), result back into LDS as hi/lo ----
  {
    f32x4 acc[8];
#pragma unroll
    for (int n = 0; n < 8; ++n) acc[n] = (f32x4){0.f, 0.f, 0.f, 0.f};
#pragma unroll
    for (int ks = 0; ks < 4; ++ks) {
      short8 a_h = *(const short8*)&ahi[lbase + ks * 32 + koff];
      short8 a_l = *(const short8*)&alo[lbase + ks * 32 + koff];
#pragma unroll
      for (int n = 0; n < 8; ++n) {
        int widx = (n * 16 + colb) * 128 + ks * 32 + koff;
        short8 b_h = *(const short8*)&W1hi[widx];
        short8 b_l = *(const short8*)&W1lo[widx];
        acc[n] = __builtin_amdgcn_mfma_f32_16x16x32_bf16(a_h, b_h, acc[n], 0, 0, 0);
        acc[n] = __builtin_amdgcn_mfma_f32_16x16x32_bf16(a_h, b_l, acc[n], 0, 0, 0);
        acc[n] = __builtin_amdgcn_mfma_f32_16x16x32_bf16(a_l, b_h, acc[n], 0, 0, 0);
      }
    }
    __syncthreads();  // all reads of ahi/alo done; overwrite with C1
#pragma unroll
    for (int n = 0; n < 8; ++n) {
      float bv = bias1[n * 16 + colb];
#pragma unroll
      for (int r = 0; r < 4; ++r) {
        float v = fmaxf(acc[n][r] + bv, 0.f);
        ushort vh = f2b(v);
        ushort vl = f2b(v - b2f(vh));
        int rr = w * 16 + rbase + r;
        ahi[rr * 136 + n * 16 + colb] = vh;
        alo[rr * 136 + n * 16 + colb] = vl;
      }
    }
  }
  __syncthreads();

  // ---- phase 3: GEMM2 = relu(C1 @ W2 + b2), restage f32, coalesced store ----
  {
    f32x4 acc[8];
#pragma unroll
    for (int n = 0; n < 8; ++n) acc[n] = (f32x4){0.f, 0.f, 0.f, 0.f};
#pragma unroll
    for (int ks = 0; ks < 4; ++ks) {
      short8 a_h = *(const short8*)&ahi[lbase + ks * 32 + koff];
      short8 a_l = *(const short8*)&alo[lbase + ks * 32 + koff];
#pragma unroll
      for (int n = 0; n < 8; ++n) {
        int widx = (n * 16 + colb) * 128 + ks * 32 + koff;
        short8 b_h = *(const short8*)&W2hi[widx];
        short8 b_l = *(const short8*)&W2lo[widx];
        acc[n] = __builtin_amdgcn_mfma_f32_16x16x32_bf16(a_h, b_h, acc[n], 0, 0, 0);
        acc[n] = __builtin_amdgcn_mfma_f32_16x16x32_bf16(a_h, b_l, acc[n], 0, 0, 0);
        acc[n] = __builtin_amdgcn_mfma_f32_16x16x32_bf16(a_l, b_h, acc[n], 0, 0, 0);
      }
    }
    __syncthreads();  // all reads done; reuse smem as f32 C
#pragma unroll
    for (int n = 0; n < 8; ++n) {
      float bv = bias2[n * 16 + colb];
#pragma unroll
      for (int r = 0; r < 4; ++r) {
        float v = fmaxf(acc[n][r] + bv, 0.f);
        ldsC[(w * 16 + rbase + r) * 132 + n * 16 + colb] = v;
      }
    }
  }
  __syncthreads();

  for (int c = t; c < 2048; c += 256) {
    int r = c >> 5;
    int c4 = (c & 31) << 2;
    int gr = row0 + r;
    if (gr < M) {
      f32x4 v;
      v[0] = ldsC[r * 132 + c4 + 0];
      v[1] = ldsC[r * 132 + c4 + 1];
      v[2] = ldsC[r * 132 + c4 + 2];
      v[3] = ldsC[r * 132 + c4 + 3];
      *(f32x4*)&hout[(size_t)gr * 128 + c4] = v;
    }
  }
}

// ---------------- global add pool: wave-per-64-node-chunk, atomic flush ----------------
__global__ __launch_bounds__(256) void k_pool(const float* __restrict__ h,
                                              const int* __restrict__ batch,
                                              float* __restrict__ g, int n_nodes) {
  int wave = (blockIdx.x * 256 + threadIdx.x) >> 6;
  int lane = threadIdx.x & 63;
  int n0 = wave * 64;
  if (n0 >= n_nodes) return;
  int n1 = n0 + 64;
  if (n1 > n_nodes) n1 = n_nodes;
  const float2* base = (const float2*)h;
  float accx = 0.f, accy = 0.f;
  int curg = batch[n0];
  int lastg = batch[n1 - 1];
  if (curg == lastg) {
    int n = n0;
    for (; n + 4 <= n1; n += 4) {
      float2 v0 = base[(size_t)n * 64 + lane];
      float2 v1 = base[(size_t)(n + 1) * 64 + lane];
      float2 v2 = base[(size_t)(n + 2) * 64 + lane];
      float2 v3 = base[(size_t)(n + 3) * 64 + lane];
      accx += (v0.x + v1.x) + (v2.x + v3.x);
      accy += (v0.y + v1.y) + (v2.y + v3.y);
    }
    for (; n < n1; ++n) {
      float2 v = base[(size_t)n * 64 + lane];
      accx += v.x; accy += v.y;
    }
    atomicAdd(&g[curg * 128 + 2 * lane], accx);
    atomicAdd(&g[curg * 128 + 2 * lane + 1], accy);
  } else {
    for (int n = n0; n < n1; ++n) {
      int b = batch[n];
      if (b != curg) {
        atomicAdd(&g[curg * 128 + 2 * lane], accx);
        atomicAdd(&g[curg * 128 + 2 * lane + 1], accy);
        accx = 0.f; accy = 0.f; curg = b;
      }
      float2 v = base[(size_t)n * 64 + lane];
      accx += v.x; accy += v.y;
    }
    atomicAdd(&g[curg * 128 + 2 * lane], accx);
    atomicAdd(&g[curg * 128 + 2 * lane + 1], accy);
  }
}

// ---------------- head: fc1+relu, fc2, log_softmax ----------------
__global__ __launch_bounds__(128) void k_head(const float* __restrict__ g,
                                              const float* __restrict__ fc1w,
                                              const float* __restrict__ fc1b,
                                              const float* __restrict__ fc2w,
                                              const float* __restrict__ fc2b,
                                              float* __restrict__ out) {
  __shared__ float gs[128], a1[128], lg[696];
  __shared__ float wred[2];
  int gr = blockIdx.x, t = threadIdx.x;
  gs[t] = g[gr * 128 + t];
  __syncthreads();
  float acc = fc1b[t];
  for (int k = 0; k < 128; ++k) acc += gs[k] * fc1w[k * 128 + t];
  a1[t] = fmaxf(acc, 0.f);
  __syncthreads();
  for (int c = t; c < 696; c += 128) {
    float s = fc2b[c];
    for (int k = 0; k < 128; ++k) s += a1[k] * fc2w[k * 696 + c];
    lg[c] = s;
  }
  __syncthreads();
  float m = -__builtin_inff();
  for (int c = t; c < 696; c += 128) m = fmaxf(m, lg[c]);
  for (int d = 32; d; d >>= 1) m = fmaxf(m, __shfl_xor(m, d, 64));
  if ((t & 63) == 0) wred[t >> 6] = m;
  __syncthreads();
  m = fmaxf(wred[0], wred[1]);
  __syncthreads();
  float se = 0.f;
  for (int c = t; c < 696; c += 128) se += expf(lg[c] - m);
  for (int d = 32; d; d >>= 1) se += __shfl_xor(se, d, 64);
  __shared__ float wred2[2];
  if ((t & 63) == 0) wred2[t >> 6] = se;
  __syncthreads();
  float lse = m + logf(wred2[0] + wred2[1]);
  for (int c = t; c < 696; c += 128) out[gr * 696 + c] = lg[c] - lse;
}

extern "C" void kernel_launch(void* const* d_in, const int* in_sizes, int n_in,
                              void* d_out, int out_size, void* d_ws, size_t ws_size,
                              hipStream_t stream) {
  const float* x    = (const float*)d_in[0];
  const int*   ei   = (const int*)d_in[1];
  const int*   batch= (const int*)d_in[2];
  const float* W1s  = (const float*)d_in[3];
  const float* b1s  = (const float*)d_in[4];
  const float* W2s  = (const float*)d_in[5];
  const float* b2s  = (const float*)d_in[6];
  const float* fc1w = (const float*)d_in[7];
  const float* fc1b = (const float*)d_in[8];
  const float* fc2w = (const float*)d_in[9];
  const float* fc2b = (const float*)d_in[10];
  float* out = (float*)d_out;

  char* ws = (char*)d_ws;
  size_t off = 0;
  auto alloc = [&](size_t bytes) -> void* {
    void* p = ws + off;
    off = (off + bytes + 255) & ~(size_t)255;
    return p;
  };
  float* hA     = (float*)alloc((size_t)N_NODESC * 128 * 4);
  float* hB     = (float*)alloc((size_t)N_NODESC * 128 * 4);
  int*   col    = (int*)alloc((size_t)N_EDGESC * 4);
  int*   rowptr = (int*)alloc((size_t)(N_NODESC + 1) * 4);
  int*   cursor = (int*)alloc((size_t)(N_NODESC + 1) * 4);
  int*   bsums  = (int*)alloc(128 * 4);
  float* g      = (float*)alloc(64 * 128 * 4);
  ushort* wthi  = (ushort*)alloc((size_t)8 * 16384 * 2);
  ushort* wtlo  = (ushort*)alloc((size_t)8 * 16384 * 2);

  const int n_scan = N_NODESC + 1;
  const int NB = (n_scan + 1023) / 1024;  // 98

  // CSR build (cursor doubles as counts)
  hipMemsetAsync(cursor, 0, (size_t)(N_NODESC + 1) * 4, stream);
  k_hist<<<dim3((N_EDGESC + 255) / 256), dim3(256), 0, stream>>>(ei, cursor, N_EDGESC);
  k_scan1<<<dim3(NB), dim3(1024), 0, stream>>>(cursor, rowptr, bsums, n_scan);
  k_scan2<<<dim3(1), dim3(64), 0, stream>>>(bsums, NB);
  k_scan3<<<dim3(NB), dim3(1024), 0, stream>>>(rowptr, bsums, cursor, n_scan);
  k_scatter<<<dim3((N_EDGESC + 255) / 256), dim3(256), 0, stream>>>(ei, cursor, col, N_EDGESC);

  // weight preprocessing
  k_wsplit<<<dim3(512), dim3(256), 0, stream>>>(W1s, W2s, wthi, wtlo);

  // 4 fused GIN layers (ping-pong buffers; gather reads random rows so no in-place)
  const int NBLK = (N_NODESC + 63) / 64;  // 1563
  const float* hin = x;
  float* houts[4] = {hA, hB, hA, hB};
  for (int L = 0; L < 4; ++L) {
    float* hout = houts[L];
    k_layer<<<dim3(NBLK), dim3(256), 0, stream>>>(
        hin, rowptr, col,
        wthi + (size_t)L * 16384, wtlo + (size_t)L * 16384,
        wthi + (size_t)(4 + L) * 16384, wtlo + (size_t)(4 + L) * 16384,
        b1s + L * 128, b2s + L * 128, hout, N_NODESC);
    hin = hout;
  }

  // pool + head
  hipMemsetAsync(g, 0, 64 * 128 * 4, stream);
  k_pool<<<dim3((N_NODESC + 255) / 256), dim3(256), 0, stream>>>(hB, batch, g, N_NODESC);
  k_head<<<dim3(64), dim3(128), 0, stream>>>(g, fc1w, fc1b, fc2w, fc2b, out);
}